// Round 8
// baseline (246.737 us; speedup 1.0000x reference)
//
#include <hip/hip_runtime.h>
#include <math.h>

#define CLAMPV 1000000.0f
#define PI_F     3.14159274f
#define HALFPI_F 1.57079633f
#define LN2_F    0.69314718f      // ln2
#define L2E_F    1.44269504f      // 1/ln2
#define C1_F     0.17328680f      // ln2/4      : exp2-arg coeff, complex nodes (log2 of |.|^2)
#define C2_F     0.05515890f      // ln2/(4*pi) : rev-arg coeff, complex nodes
#define C2R_F    0.11031780f      // ln2/(2*pi) : rev-arg coeff, real-child nodes

#define NBIN 4096

typedef float v2f __attribute__((ext_vector_type(2)));

__device__ __forceinline__ v2f vb(float s) { return (v2f){s, s}; }
__device__ __forceinline__ v2f vfma(v2f a, v2f b, v2f c) { return __builtin_elementwise_fma(a, b, c); }

// Wave-uniform gate pointer -> s_load on the scalar pipe.
__device__ __forceinline__ const float* gptr(const float* __restrict__ g, int node) {
    return g + 6 * __builtin_amdgcn_readfirstlane(node);
}

// monotone float -> sortable uint
__device__ __forceinline__ unsigned sortkey(float x) {
    unsigned u = __float_as_uint(x);
    u ^= (unsigned)(((int)u) >> 31) | 0x80000000u;
    return u;
}

// sanitize: nan -> 0, clamp to [-1e6,1e6] (med3 absorbs +-inf)
__device__ __forceinline__ v2f sanitv(v2f v) {
    v2f c;
    c.x = __builtin_amdgcn_fmed3f(v.x, -CLAMPV, CLAMPV);
    c.y = __builtin_amdgcn_fmed3f(v.y, -CLAMPV, CLAMPV);
    c.x = (v.x != v.x) ? 0.0f : c.x;
    c.y = (v.y != v.y) ? 0.0f : c.y;
    return c;
}

// packed fast atan2, deg-9 minimax; (+0, x<0) -> +pi matches numpy for the
// exact-zero-imag chains (imag forced to +0 upstream).
__device__ __forceinline__ v2f fatan2v(v2f y, v2f x) {
    v2f ax = __builtin_elementwise_abs(x);
    v2f ay = __builtin_elementwise_abs(y);
    v2f mx = __builtin_elementwise_max(ax, ay);
    v2f mn = __builtin_elementwise_min(ax, ay);
    v2f r  = (v2f){__builtin_amdgcn_rcpf(mx.x), __builtin_amdgcn_rcpf(mx.y)};
    v2f t  = mn * r;
    v2f z  = t * t;
    v2f p  = vfma(z, vfma(z, vfma(z, vfma(z,
             vb(0.02083510f), vb(-0.08513300f)), vb(0.18014100f)), vb(-0.33029950f)),
             vb(0.99986600f));
    p = p * t;
    p.x = (ay.x > ax.x) ? (HALFPI_F - p.x) : p.x;
    p.y = (ay.y > ax.y) ? (HALFPI_F - p.y) : p.y;
    p.x = (x.x < 0.0f) ? (PI_F - p.x) : p.x;
    p.y = (x.y < 0.0f) ? (PI_F - p.y) : p.y;
    p.x = copysignf(p.x, y.x);
    p.y = copysignf(p.y, y.y);
    return p;
}

// exp2/sin/cos tail from pre-folded args: r = 2^e ; angle = f0 revolutions.
__device__ __forceinline__ void exp_tailv(v2f e, v2f f0, v2f& ore, v2f& oim) {
    v2f r = (v2f){__builtin_amdgcn_exp2f(e.x), __builtin_amdgcn_exp2f(e.y)};
    v2f f = (v2f){__builtin_amdgcn_fractf(f0.x), __builtin_amdgcn_fractf(f0.y)};
    v2f sn = (v2f){__builtin_amdgcn_sinf(f.x), __builtin_amdgcn_sinf(f.y)};
    v2f cs = (v2f){__builtin_amdgcn_cosf(f.x), __builtin_amdgcn_cosf(f.y)};
    ore = sanitv(r * cs);
    oim = sanitv(r * sn);
}

// Real-positive fast path body: children real, u > 0, v > 0 across the wave.
//   out = ( min(2^(ln2*log2(u)*log2(v)), 1e6), +0 )
__device__ __forceinline__ void fast_rp(v2f ure, v2f vre, v2f& ore, v2f& oim) {
    v2f L2u = (v2f){__builtin_amdgcn_logf(ure.x), __builtin_amdgcn_logf(ure.y)};
    v2f L2v = (v2f){__builtin_amdgcn_logf(vre.x), __builtin_amdgcn_logf(vre.y)};
    v2f e = (vb(LN2_F) * L2u) * L2v;
    v2f r = (v2f){__builtin_amdgcn_exp2f(e.x), __builtin_amdgcn_exp2f(e.y)};
    v2f c = __builtin_elementwise_min(r, vb(CLAMPV));
    c.x = (r.x != r.x) ? 0.0f : c.x;
    c.y = (r.y != r.y) ? 0.0f : c.y;
    ore = c;
    oim = vb(0.0f);
}

// General node (children may be complex). Wave-uniform fast path when every
// lane has real children and strictly positive u, v; otherwise exact complex.
__device__ __forceinline__ void node_any(
    v2f lre, v2f lim, v2f rre, v2f rim,
    v2f x, const float* __restrict__ g,
    v2f& ore, v2f& oim)
{
    float g0 = g[0], g1 = g[1], g2 = g[2], g3 = g[3], g4 = g[4], g5 = g[5];
    v2f ure = vfma(vb(g2), lre, vfma(vb(g1), x, vb(g0)));
    v2f vre = vfma(vb(g5), rre, vfma(vb(g4), x, vb(g3)));
    v2f mn = __builtin_elementwise_min(ure, vre);

    unsigned long long bad =
        __ballot(lim.x != 0.0f) | __ballot(lim.y != 0.0f) |
        __ballot(rim.x != 0.0f) | __ballot(rim.y != 0.0f) |
        __ballot(mn.x <= 0.0f)  | __ballot(mn.y <= 0.0f);

    if (bad == 0ULL) {
        fast_rp(ure, vre, ore, oim);
    } else {
        // full complex path (exact; fma(g2, lim, +0) forces -0 -> +0, which is
        // load-bearing for the atan2 branch choice when a child's imag is zero)
        v2f uim = vfma(vb(g2), lim, vb(0.0f));
        v2f vim = vfma(vb(g5), rim, vb(0.0f));

        v2f nu = vfma(ure, ure, uim * uim);
        v2f nv = vfma(vre, vre, vim * vim);
        v2f L2u = (v2f){__builtin_amdgcn_logf(nu.x), __builtin_amdgcn_logf(nu.y)};
        v2f L2v = (v2f){__builtin_amdgcn_logf(nv.x), __builtin_amdgcn_logf(nv.y)};
        v2f Au = fatan2v(uim, ure);
        v2f Av = fatan2v(vim, vre);

        v2f t2 = vb(L2E_F) * (Au * Av);
        v2f e  = vfma(vb(C1_F) * L2u, L2v, -t2);
        v2f s2 = vfma(L2u, Av, Au * L2v);
        v2f f0 = vb(C2_F) * s2;
        exp_tailv(e, f0, ore, oim);
    }
}

// Round-0 node: children are real leaf values.
__device__ __forceinline__ void node_r0(
    v2f l, v2f r, v2f x, const float* __restrict__ g,
    v2f& ore, v2f& oim)
{
    float g0 = g[0], g1 = g[1], g2 = g[2], g3 = g[3], g4 = g[4], g5 = g[5];
    v2f u = vfma(vb(g2), l, vfma(vb(g1), x, vb(g0)));
    v2f v = vfma(vb(g5), r, vfma(vb(g4), x, vb(g3)));
    v2f mn = __builtin_elementwise_min(u, v);

    unsigned long long bad = __ballot(mn.x <= 0.0f) | __ballot(mn.y <= 0.0f);

    if (bad == 0ULL) {
        fast_rp(u, v, ore, oim);
    } else {
        v2f au = __builtin_elementwise_abs(u);
        v2f av = __builtin_elementwise_abs(v);
        v2f L2u = (v2f){__builtin_amdgcn_logf(au.x), __builtin_amdgcn_logf(au.y)};
        v2f L2v = (v2f){__builtin_amdgcn_logf(av.x), __builtin_amdgcn_logf(av.y)};
        v2f Au, Av;
        Au.x = (u.x < 0.0f) ? PI_F : 0.0f;
        Au.y = (u.y < 0.0f) ? PI_F : 0.0f;
        Av.x = (v.x < 0.0f) ? PI_F : 0.0f;
        Av.y = (v.y < 0.0f) ? PI_F : 0.0f;

        v2f t2 = vb(L2E_F) * (Au * Av);
        v2f e  = vfma(vb(LN2_F) * L2u, L2v, -t2);
        v2f s2 = vfma(L2u, Av, Au * L2v);
        v2f f0 = vb(C2R_F) * s2;
        exp_tailv(e, f0, ore, oim);
    }
}

// ---------- counting-sort aux kernels (cluster elements by x) ----------

__global__ void eml_zero_hist(unsigned* __restrict__ hist) {
    hist[blockIdx.x * 1024 + threadIdx.x] = 0u;   // grid 4, block 1024
}

__global__ void eml_hist(const float* __restrict__ x, unsigned* __restrict__ hist, int n) {
    int i = blockIdx.x * 1024 + threadIdx.x;
    if (i < n) atomicAdd(&hist[sortkey(x[i]) >> 20], 1u);
}

// single block, 1024 threads, 4 bins each: exclusive prefix -> offs
__global__ void eml_scan(const unsigned* __restrict__ hist, unsigned* __restrict__ offs) {
    __shared__ unsigned part[1024];
    int t = threadIdx.x;
    unsigned h0 = hist[4*t], h1 = hist[4*t+1], h2 = hist[4*t+2], h3 = hist[4*t+3];
    unsigned sum = h0 + h1 + h2 + h3;
    part[t] = sum;
    __syncthreads();
    for (int d = 1; d < 1024; d <<= 1) {
        unsigned v = (t >= d) ? part[t - d] : 0u;
        __syncthreads();
        part[t] += v;
        __syncthreads();
    }
    unsigned excl = part[t] - sum;
    offs[4*t]   = excl;
    offs[4*t+1] = excl + h0;
    offs[4*t+2] = excl + h0 + h1;
    offs[4*t+3] = excl + h0 + h1 + h2;
}

__global__ void eml_scatter(const float* __restrict__ x, unsigned* __restrict__ offs,
                            unsigned* __restrict__ sidx, float* __restrict__ xs, int n) {
    int i = blockIdx.x * 1024 + threadIdx.x;
    if (i < n) {
        float xv = x[i];
        unsigned pos = atomicAdd(&offs[sortkey(xv) >> 20], 1u);
        sidx[pos] = (unsigned)i;
        xs[pos]   = xv;
    }
}

// ---------- main kernel ----------
// Block: 64 lanes x 16 subtrees (1024 threads = 16 waves). Each lane owns 2
// rank-positions p0 = blk*128+lane and p0+64 (x-sorted -> waves are x-adjacent,
// so the wave-uniform fast/slow ballot almost always goes fast). Output is
// scattered back through sidx. Falls back to identity order if sidx==nullptr.
__global__ __launch_bounds__(1024, 8) void EMLTree1DLinear_kernel(
    const float* __restrict__ x_g,      // [batch] original order
    const float* __restrict__ leaf_g,   // [1024][2]
    const float* __restrict__ gate_g,   // [1023][2][3] flat
    const unsigned* __restrict__ sidx,  // [batch] sorted rank -> element id (or null)
    const float* __restrict__ xs,       // [batch] x in sorted order (or null)
    float* __restrict__ out,            // [batch][2] interleaved complex (or [batch] real)
    int batch, int out_real_only)
{
    __shared__ float4 s_t[16][64];        // 16384 B: round-5 subtree roots / tail scratch

    const int lane = threadIdx.x;         // 0..63
    const int s    = threadIdx.y;         // subtree, 0..15

    const int p0 = blockIdx.x * 128 + lane;
    const v2f x2 = sidx ? (v2f){xs[p0], xs[p0 + 64]}
                        : (v2f){x_g[p0], x_g[p0 + 64]};

    v2f cAre, cAim, cBre, cBim, rootre, rootim;

    // 4 groups of 16 leaves; rolled to keep the dual-path body I$-resident.
#pragma clang loop unroll(disable)
    for (int q = 0; q < 4; ++q) {
        const int jq = 64 * s + 16 * q;    // leftmost leaf of this group
        v2f r2re[2], r2im[2];
        v2f h1re = vb(0.0f), h1im = vb(0.0f);
        v2f cre, cim;

#pragma unroll
        for (int p = 0; p < 4; ++p) {
            const int j = jq + 4 * p;
            // 4 leaves via scalar loads (wave-uniform address)
            const float* L = leaf_g + 2 * __builtin_amdgcn_readfirstlane(j);
            v2f l0 = vfma(vb(L[1]), x2, vb(L[0]));
            v2f l1 = vfma(vb(L[3]), x2, vb(L[2]));
            v2f l2 = vfma(vb(L[5]), x2, vb(L[4]));
            v2f l3 = vfma(vb(L[7]), x2, vb(L[6]));

            // round 0: nodes (j>>1), (j>>1)+1
            v2f Are, Aim, Bre, Bim;
            node_r0(l0, l1, x2, gptr(gate_g, j >> 1), Are, Aim);
            node_r0(l2, l3, x2, gptr(gate_g, (j >> 1) + 1), Bre, Bim);

            // round 1: node 512 + (j>>2)
            v2f r1re, r1im;
            node_any(Are, Aim, Bre, Bim, x2, gptr(gate_g, 512 + (j >> 2)), r1re, r1im);

            if (p & 1) {
                // round 2: node 768 + (j>>3)
                node_any(h1re, h1im, r1re, r1im, x2,
                         gptr(gate_g, 768 + (j >> 3)), r2re[p >> 1], r2im[p >> 1]);
            } else {
                h1re = r1re; h1im = r1im;
            }
        }
        // round 3: node 896 + (jq>>4)
        node_any(r2re[0], r2im[0], r2re[1], r2im[1], x2,
                 gptr(gate_g, 896 + (jq >> 4)), cre, cim);

        // rounds 4-5: static register merge (positions 4s+q at round 3)
        if (q == 0) {
            cAre = cre; cAim = cim;
        } else if (q == 1) {
            node_any(cAre, cAim, cre, cim, x2, gptr(gate_g, 960 + 2 * s), cBre, cBim);
        } else if (q == 2) {
            cAre = cre; cAim = cim;
        } else {
            v2f tre, tim;
            node_any(cAre, cAim, cre, cim, x2, gptr(gate_g, 961 + 2 * s), tre, tim);
            node_any(cBre, cBim, tre, tim, x2, gptr(gate_g, 992 + s), rootre, rootim);
        }
    }

    // round-5 subtree root -> LDS; single barrier; wave 0 finishes the tree.
    s_t[s][lane] = make_float4(rootre.x, rootre.y, rootim.x, rootim.y);
    __syncthreads();
    if (s != 0) return;

    // rounds 6..9 via rolled loops (wave0-only, LDS scratch, no barriers).
#pragma clang loop unroll(disable)
    for (int L = 6; L <= 9; ++L) {
        const int cnt  = 1 << (9 - L);
        const int base = 1024 - (1 << (10 - L));
#pragma clang loop unroll(disable)
        for (int j = 0; j < cnt; ++j) {
            float4 a = s_t[2 * j][lane], b = s_t[2 * j + 1][lane];
            v2f rre, rim;
            node_any((v2f){a.x, a.y}, (v2f){a.z, a.w},
                     (v2f){b.x, b.y}, (v2f){b.z, b.w},
                     x2, gptr(gate_g, base + j), rre, rim);
            s_t[j][lane] = make_float4(rre.x, rre.y, rim.x, rim.y);
        }
    }

    float4 fin = s_t[0][lane];
    const int i0 = sidx ? (int)sidx[p0]      : p0;
    const int i1 = sidx ? (int)sidx[p0 + 64] : p0 + 64;
    if (out_real_only) {
        out[i0] = fin.x;
        out[i1] = fin.y;
    } else {
        reinterpret_cast<float2*>(out)[i0] = make_float2(fin.x, fin.z);
        reinterpret_cast<float2*>(out)[i1] = make_float2(fin.y, fin.w);
    }
}

extern "C" void kernel_launch(void* const* d_in, const int* in_sizes, int n_in,
                              void* d_out, int out_size, void* d_ws, size_t ws_size,
                              hipStream_t stream) {
    const float* x    = (const float*)d_in[0];
    const float* leaf = (const float*)d_in[1];
    const float* gate = (const float*)d_in[2];
    float* out = (float*)d_out;
    const int batch = in_sizes[0];

    const int out_real_only = (out_size == batch) ? 1 : 0;

    // ws layout: hist[4096] | offs[4096] | sidx[batch] | xs[batch]
    const size_t need = (size_t)NBIN * 4 * 2 + (size_t)batch * 4 * 2;
    unsigned* hist = (unsigned*)d_ws;
    unsigned* offs = hist + NBIN;
    unsigned* sidx = offs + NBIN;
    float*    xs   = (float*)(sidx + batch);

    const bool use_sort = (ws_size >= need) && (batch % 128 == 0);

    if (use_sort) {
        hipLaunchKernelGGL(eml_zero_hist, dim3(NBIN / 1024), dim3(1024), 0, stream, hist);
        hipLaunchKernelGGL(eml_hist, dim3((batch + 1023) / 1024), dim3(1024), 0, stream,
                           x, hist, batch);
        hipLaunchKernelGGL(eml_scan, dim3(1), dim3(1024), 0, stream, hist, offs);
        hipLaunchKernelGGL(eml_scatter, dim3((batch + 1023) / 1024), dim3(1024), 0, stream,
                           x, offs, sidx, xs, batch);
    }

    dim3 block(64, 16);
    dim3 grid(batch / 128);
    hipLaunchKernelGGL(EMLTree1DLinear_kernel, grid, block, 0, stream,
                       x, leaf, gate,
                       use_sort ? sidx : (const unsigned*)nullptr,
                       use_sort ? xs : (const float*)nullptr,
                       out, batch, out_real_only);
}

// Round 9
// 128.833 us; speedup vs baseline: 1.9152x; 1.9152x over previous
//
#include <hip/hip_runtime.h>
#include <math.h>

#define CLAMPV 1000000.0f
#define PI_F     3.14159274f
#define HALFPI_F 1.57079633f
#define LN2_F    0.69314718f      // ln2
#define L2E_F    1.44269504f      // 1/ln2
#define C1_F     0.17328680f      // ln2/4      : exp2-arg coeff, complex nodes (log2 of |.|^2)
#define C2_F     0.05515890f      // ln2/(4*pi) : rev-arg coeff, complex nodes
#define C2R_F    0.11031780f      // ln2/(2*pi) : rev-arg coeff, real-child nodes

typedef float v2f __attribute__((ext_vector_type(2)));

__device__ __forceinline__ v2f vb(float s) { return (v2f){s, s}; }
__device__ __forceinline__ v2f vfma(v2f a, v2f b, v2f c) { return __builtin_elementwise_fma(a, b, c); }

// Wave-uniform gate pointer -> s_load on the scalar pipe.
__device__ __forceinline__ const float* gptr(const float* __restrict__ g, int node) {
    return g + 6 * __builtin_amdgcn_readfirstlane(node);
}

// # set bits of m below this lane
__device__ __forceinline__ unsigned rank_below(unsigned long long m) {
    return __builtin_amdgcn_mbcnt_hi((unsigned)(m >> 32),
           __builtin_amdgcn_mbcnt_lo((unsigned)m, 0u));
}

// ---------------- pass-1: branch-free real-positive evaluation + taint ----------------
// One tree node assuming real children. Taint tracker: tmin = min over all
// nodes of min(u,v); element needs the exact pass iff tmin <= 0 (or NaN).
// For untainted elements this is the exact fast formula (validated R7/R8);
// for tainted elements downstream values are garbage and are discarded.
__device__ __forceinline__ v2f fnode(v2f l, v2f r, v2f x,
                                     const float* __restrict__ g, v2f& tmin) {
    float g0 = g[0], g1 = g[1], g2 = g[2], g3 = g[3], g4 = g[4], g5 = g[5];
    v2f u = vfma(vb(g2), l, vfma(vb(g1), x, vb(g0)));
    v2f v = vfma(vb(g5), r, vfma(vb(g4), x, vb(g3)));
    tmin = __builtin_elementwise_min(tmin, __builtin_elementwise_min(u, v));
    v2f L2u = (v2f){__builtin_amdgcn_logf(u.x), __builtin_amdgcn_logf(u.y)};
    v2f L2v = (v2f){__builtin_amdgcn_logf(v.x), __builtin_amdgcn_logf(v.y)};
    v2f e = (vb(LN2_F) * L2u) * L2v;
    v2f rr = (v2f){__builtin_amdgcn_exp2f(e.x), __builtin_amdgcn_exp2f(e.y)};
    return __builtin_elementwise_min(rr, vb(CLAMPV));   // +inf -> 1e6; r >= 0
}

// Block: 64 lanes x 16 subtrees (1024 thr). Lane owns elements e0, e0+64,
// 2-wide packed. Whole tree evaluated fast-real, no branches. Wave 0 writes
// untainted outputs and compacts tainted element ids into `list`.
__global__ __launch_bounds__(1024, 8) void eml_fast_taint(
    const float* __restrict__ x_g, const float* __restrict__ leaf_g,
    const float* __restrict__ gate_g, float* __restrict__ out,
    unsigned* __restrict__ cnt, unsigned* __restrict__ list,
    int batch, int out_real_only)
{
    __shared__ float4 s_t[16][64];   // (root0, root1, tmin0, tmin1)

    const int lane = threadIdx.x;    // 0..63
    const int s    = threadIdx.y;    // subtree 0..15
    const int e0 = blockIdx.x * 128 + lane;
    const v2f x2 = (v2f){x_g[e0], x_g[e0 + 64]};

    v2f tmin = vb(1.0f);
    v2f cA, cB, root;

#pragma clang loop unroll(disable)
    for (int q = 0; q < 4; ++q) {
        const int jq = 64 * s + 16 * q;
        v2f r2[2], h1, c;
#pragma unroll
        for (int p = 0; p < 4; ++p) {
            const int j = jq + 4 * p;
            const float* L = leaf_g + 2 * __builtin_amdgcn_readfirstlane(j);
            v2f l0 = vfma(vb(L[1]), x2, vb(L[0]));
            v2f l1 = vfma(vb(L[3]), x2, vb(L[2]));
            v2f l2 = vfma(vb(L[5]), x2, vb(L[4]));
            v2f l3 = vfma(vb(L[7]), x2, vb(L[6]));

            v2f A  = fnode(l0, l1, x2, gptr(gate_g, j >> 1), tmin);
            v2f B  = fnode(l2, l3, x2, gptr(gate_g, (j >> 1) + 1), tmin);
            v2f r1 = fnode(A, B, x2, gptr(gate_g, 512 + (j >> 2)), tmin);
            if (p & 1) r2[p >> 1] = fnode(h1, r1, x2, gptr(gate_g, 768 + (j >> 3)), tmin);
            else       h1 = r1;
        }
        c = fnode(r2[0], r2[1], x2, gptr(gate_g, 896 + (jq >> 4)), tmin);
        if      (q == 0) cA = c;
        else if (q == 1) cB = fnode(cA, c, x2, gptr(gate_g, 960 + 2 * s), tmin);
        else if (q == 2) cA = c;
        else {
            v2f t = fnode(cA, c, x2, gptr(gate_g, 961 + 2 * s), tmin);
            root  = fnode(cB, t, x2, gptr(gate_g, 992 + s), tmin);
        }
    }

    s_t[s][lane] = make_float4(root.x, root.y, tmin.x, tmin.y);
    __syncthreads();
    if (s != 0) return;

    // tail rounds 6..9 (wave0 only), carrying tmin through
#pragma clang loop unroll(disable)
    for (int L = 6; L <= 9; ++L) {
        const int cntL = 1 << (9 - L);
        const int base = 1024 - (1 << (10 - L));
#pragma clang loop unroll(disable)
        for (int j = 0; j < cntL; ++j) {
            float4 a = s_t[2 * j][lane], b = s_t[2 * j + 1][lane];
            v2f tm = __builtin_elementwise_min((v2f){a.z, a.w}, (v2f){b.z, b.w});
            v2f r  = fnode((v2f){a.x, a.y}, (v2f){b.x, b.y}, x2,
                           gptr(gate_g, base + j), tm);
            s_t[j][lane] = make_float4(r.x, r.y, tm.x, tm.y);
        }
    }

    float4 fin = s_t[0][lane];
    const bool t0 = !(fin.z > 0.0f);   // taint iff tmin <= 0 or NaN
    const bool t1 = !(fin.w > 0.0f);

    // untainted: final value is real positive, imag = +0 (exact)
    if (!t0) {
        if (out_real_only) out[e0] = fin.x;
        else reinterpret_cast<float2*>(out)[e0] = make_float2(fin.x, 0.0f);
    }
    if (!t1) {
        if (out_real_only) out[e0 + 64] = fin.y;
        else reinterpret_cast<float2*>(out)[e0 + 64] = make_float2(fin.y, 0.0f);
    }

    // compact tainted ids (2 ballots + <=1 atomic per wave)
    unsigned long long m0 = __ballot(t0), m1 = __ballot(t1);
    int n0 = __popcll(m0), n1 = __popcll(m1);
    unsigned base = 0;
    if (lane == 0 && (n0 + n1)) base = atomicAdd(cnt, (unsigned)(n0 + n1));
    base = __shfl(base, 0);
    if (t0) list[base + rank_below(m0)] = (unsigned)e0;
    if (t1) list[base + n0 + rank_below(m1)] = (unsigned)(e0 + 64);
}

// ---------------- pass-2: exact kernel over the tainted list ----------------

__device__ __forceinline__ v2f sanitv(v2f v) {
    v2f c;
    c.x = __builtin_amdgcn_fmed3f(v.x, -CLAMPV, CLAMPV);
    c.y = __builtin_amdgcn_fmed3f(v.y, -CLAMPV, CLAMPV);
    c.x = (v.x != v.x) ? 0.0f : c.x;
    c.y = (v.y != v.y) ? 0.0f : c.y;
    return c;
}

__device__ __forceinline__ v2f fatan2v(v2f y, v2f x) {
    v2f ax = __builtin_elementwise_abs(x);
    v2f ay = __builtin_elementwise_abs(y);
    v2f mx = __builtin_elementwise_max(ax, ay);
    v2f mn = __builtin_elementwise_min(ax, ay);
    v2f r  = (v2f){__builtin_amdgcn_rcpf(mx.x), __builtin_amdgcn_rcpf(mx.y)};
    v2f t  = mn * r;
    v2f z  = t * t;
    v2f p  = vfma(z, vfma(z, vfma(z, vfma(z,
             vb(0.02083510f), vb(-0.08513300f)), vb(0.18014100f)), vb(-0.33029950f)),
             vb(0.99986600f));
    p = p * t;
    p.x = (ay.x > ax.x) ? (HALFPI_F - p.x) : p.x;
    p.y = (ay.y > ax.y) ? (HALFPI_F - p.y) : p.y;
    p.x = (x.x < 0.0f) ? (PI_F - p.x) : p.x;
    p.y = (x.y < 0.0f) ? (PI_F - p.y) : p.y;
    p.x = copysignf(p.x, y.x);
    p.y = copysignf(p.y, y.y);
    return p;
}

__device__ __forceinline__ void exp_tailv(v2f e, v2f f0, v2f& ore, v2f& oim) {
    v2f r = (v2f){__builtin_amdgcn_exp2f(e.x), __builtin_amdgcn_exp2f(e.y)};
    v2f f = (v2f){__builtin_amdgcn_fractf(f0.x), __builtin_amdgcn_fractf(f0.y)};
    v2f sn = (v2f){__builtin_amdgcn_sinf(f.x), __builtin_amdgcn_sinf(f.y)};
    v2f cs = (v2f){__builtin_amdgcn_cosf(f.x), __builtin_amdgcn_cosf(f.y)};
    ore = sanitv(r * cs);
    oim = sanitv(r * sn);
}

__device__ __forceinline__ void fast_rp(v2f ure, v2f vre, v2f& ore, v2f& oim) {
    v2f L2u = (v2f){__builtin_amdgcn_logf(ure.x), __builtin_amdgcn_logf(ure.y)};
    v2f L2v = (v2f){__builtin_amdgcn_logf(vre.x), __builtin_amdgcn_logf(vre.y)};
    v2f e = (vb(LN2_F) * L2u) * L2v;
    v2f r = (v2f){__builtin_amdgcn_exp2f(e.x), __builtin_amdgcn_exp2f(e.y)};
    v2f c = __builtin_elementwise_min(r, vb(CLAMPV));
    c.x = (r.x != r.x) ? 0.0f : c.x;
    c.y = (r.y != r.y) ? 0.0f : c.y;
    ore = c;
    oim = vb(0.0f);
}

__device__ __forceinline__ void node_any(
    v2f lre, v2f lim, v2f rre, v2f rim,
    v2f x, const float* __restrict__ g,
    v2f& ore, v2f& oim)
{
    float g0 = g[0], g1 = g[1], g2 = g[2], g3 = g[3], g4 = g[4], g5 = g[5];
    v2f ure = vfma(vb(g2), lre, vfma(vb(g1), x, vb(g0)));
    v2f vre = vfma(vb(g5), rre, vfma(vb(g4), x, vb(g3)));
    v2f mn = __builtin_elementwise_min(ure, vre);

    unsigned long long bad =
        __ballot(lim.x != 0.0f) | __ballot(lim.y != 0.0f) |
        __ballot(rim.x != 0.0f) | __ballot(rim.y != 0.0f) |
        __ballot(mn.x <= 0.0f)  | __ballot(mn.y <= 0.0f);

    if (bad == 0ULL) {
        fast_rp(ure, vre, ore, oim);
    } else {
        // exact complex path; fma(g2, lim, +0) forces -0 -> +0 (load-bearing
        // for the atan2 branch choice when a child's imag is exactly zero)
        v2f uim = vfma(vb(g2), lim, vb(0.0f));
        v2f vim = vfma(vb(g5), rim, vb(0.0f));

        v2f nu = vfma(ure, ure, uim * uim);
        v2f nv = vfma(vre, vre, vim * vim);
        v2f L2u = (v2f){__builtin_amdgcn_logf(nu.x), __builtin_amdgcn_logf(nu.y)};
        v2f L2v = (v2f){__builtin_amdgcn_logf(nv.x), __builtin_amdgcn_logf(nv.y)};
        v2f Au = fatan2v(uim, ure);
        v2f Av = fatan2v(vim, vre);

        v2f t2 = vb(L2E_F) * (Au * Av);
        v2f e  = vfma(vb(C1_F) * L2u, L2v, -t2);
        v2f s2 = vfma(L2u, Av, Au * L2v);
        v2f f0 = vb(C2_F) * s2;
        exp_tailv(e, f0, ore, oim);
    }
}

__device__ __forceinline__ void node_r0(
    v2f l, v2f r, v2f x, const float* __restrict__ g,
    v2f& ore, v2f& oim)
{
    float g0 = g[0], g1 = g[1], g2 = g[2], g3 = g[3], g4 = g[4], g5 = g[5];
    v2f u = vfma(vb(g2), l, vfma(vb(g1), x, vb(g0)));
    v2f v = vfma(vb(g5), r, vfma(vb(g4), x, vb(g3)));
    v2f mn = __builtin_elementwise_min(u, v);

    unsigned long long bad = __ballot(mn.x <= 0.0f) | __ballot(mn.y <= 0.0f);

    if (bad == 0ULL) {
        fast_rp(u, v, ore, oim);
    } else {
        v2f au = __builtin_elementwise_abs(u);
        v2f av = __builtin_elementwise_abs(v);
        v2f L2u = (v2f){__builtin_amdgcn_logf(au.x), __builtin_amdgcn_logf(au.y)};
        v2f L2v = (v2f){__builtin_amdgcn_logf(av.x), __builtin_amdgcn_logf(av.y)};
        v2f Au, Av;
        Au.x = (u.x < 0.0f) ? PI_F : 0.0f;
        Au.y = (u.y < 0.0f) ? PI_F : 0.0f;
        Av.x = (v.x < 0.0f) ? PI_F : 0.0f;
        Av.y = (v.y < 0.0f) ? PI_F : 0.0f;

        v2f t2 = vb(L2E_F) * (Au * Av);
        v2f e  = vfma(vb(LN2_F) * L2u, L2v, -t2);
        v2f s2 = vfma(L2u, Av, Au * L2v);
        v2f f0 = vb(C2R_F) * s2;
        exp_tailv(e, f0, ore, oim);
    }
}

// Exact kernel over tainted ranks [blk*128, blk*128+128); fixed grid with
// early block exit on count; ragged tail clamps rank (duplicate compute,
// identical redundant writes — benign).
__global__ __launch_bounds__(1024, 8) void eml_slow(
    const float* __restrict__ x_g, const float* __restrict__ leaf_g,
    const float* __restrict__ gate_g, const unsigned* __restrict__ cnt,
    const unsigned* __restrict__ list, float* __restrict__ out,
    int batch, int out_real_only)
{
    __shared__ float4 s_t[16][64];

    const unsigned count = cnt[0];
    const unsigned r0 = blockIdx.x * 128u;
    if (r0 >= count) return;

    const int lane = threadIdx.x;
    const int s    = threadIdx.y;
    const unsigned ra = min(r0 + (unsigned)lane, count - 1u);
    const unsigned rb = min(r0 + (unsigned)lane + 64u, count - 1u);
    const unsigned ia = list[ra], ib = list[rb];
    const v2f x2 = (v2f){x_g[ia], x_g[ib]};

    v2f cAre, cAim, cBre, cBim, rootre, rootim;

#pragma clang loop unroll(disable)
    for (int q = 0; q < 4; ++q) {
        const int jq = 64 * s + 16 * q;
        v2f r2re[2], r2im[2];
        v2f h1re = vb(0.0f), h1im = vb(0.0f);
        v2f cre, cim;

#pragma unroll
        for (int p = 0; p < 4; ++p) {
            const int j = jq + 4 * p;
            const float* L = leaf_g + 2 * __builtin_amdgcn_readfirstlane(j);
            v2f l0 = vfma(vb(L[1]), x2, vb(L[0]));
            v2f l1 = vfma(vb(L[3]), x2, vb(L[2]));
            v2f l2 = vfma(vb(L[5]), x2, vb(L[4]));
            v2f l3 = vfma(vb(L[7]), x2, vb(L[6]));

            v2f Are, Aim, Bre, Bim;
            node_r0(l0, l1, x2, gptr(gate_g, j >> 1), Are, Aim);
            node_r0(l2, l3, x2, gptr(gate_g, (j >> 1) + 1), Bre, Bim);

            v2f r1re, r1im;
            node_any(Are, Aim, Bre, Bim, x2, gptr(gate_g, 512 + (j >> 2)), r1re, r1im);

            if (p & 1) {
                node_any(h1re, h1im, r1re, r1im, x2,
                         gptr(gate_g, 768 + (j >> 3)), r2re[p >> 1], r2im[p >> 1]);
            } else {
                h1re = r1re; h1im = r1im;
            }
        }
        v2f cre2, cim2;
        node_any(r2re[0], r2im[0], r2re[1], r2im[1], x2,
                 gptr(gate_g, 896 + (jq >> 4)), cre2, cim2);
        cre = cre2; cim = cim2;

        if (q == 0) {
            cAre = cre; cAim = cim;
        } else if (q == 1) {
            node_any(cAre, cAim, cre, cim, x2, gptr(gate_g, 960 + 2 * s), cBre, cBim);
        } else if (q == 2) {
            cAre = cre; cAim = cim;
        } else {
            v2f tre, tim;
            node_any(cAre, cAim, cre, cim, x2, gptr(gate_g, 961 + 2 * s), tre, tim);
            node_any(cBre, cBim, tre, tim, x2, gptr(gate_g, 992 + s), rootre, rootim);
        }
    }

    s_t[s][lane] = make_float4(rootre.x, rootre.y, rootim.x, rootim.y);
    __syncthreads();
    if (s != 0) return;

#pragma clang loop unroll(disable)
    for (int L = 6; L <= 9; ++L) {
        const int cntL = 1 << (9 - L);
        const int base = 1024 - (1 << (10 - L));
#pragma clang loop unroll(disable)
        for (int j = 0; j < cntL; ++j) {
            float4 a = s_t[2 * j][lane], b = s_t[2 * j + 1][lane];
            v2f rre, rim;
            node_any((v2f){a.x, a.y}, (v2f){a.z, a.w},
                     (v2f){b.x, b.y}, (v2f){b.z, b.w},
                     x2, gptr(gate_g, base + j), rre, rim);
            s_t[j][lane] = make_float4(rre.x, rre.y, rim.x, rim.y);
        }
    }

    float4 fin = s_t[0][lane];
    if (out_real_only) {
        out[ia] = fin.x;
        out[ib] = fin.y;
    } else {
        reinterpret_cast<float2*>(out)[ia] = make_float2(fin.x, fin.z);
        reinterpret_cast<float2*>(out)[ib] = make_float2(fin.y, fin.w);
    }
}

extern "C" void kernel_launch(void* const* d_in, const int* in_sizes, int n_in,
                              void* d_out, int out_size, void* d_ws, size_t ws_size,
                              hipStream_t stream) {
    const float* x    = (const float*)d_in[0];
    const float* leaf = (const float*)d_in[1];
    const float* gate = (const float*)d_in[2];
    float* out = (float*)d_out;
    const int batch = in_sizes[0];

    const int out_real_only = (out_size == batch) ? 1 : 0;

    // ws layout: cnt (4B) | pad | list[batch]
    unsigned* cnt  = (unsigned*)d_ws;
    unsigned* list = (unsigned*)d_ws + 64;

    hipMemsetAsync(cnt, 0, sizeof(unsigned), stream);

    dim3 block(64, 16);
    dim3 grid(batch / 128);
    hipLaunchKernelGGL(eml_fast_taint, grid, block, 0, stream,
                       x, leaf, gate, out, cnt, list, batch, out_real_only);
    hipLaunchKernelGGL(eml_slow, grid, block, 0, stream,
                       x, leaf, gate, cnt, list, out, batch, out_real_only);
}